// Round 4
// baseline (353.808 us; speedup 1.0000x reference)
//
#include <hip/hip_runtime.h>

// CrossJointAttention fused kernel for MI355X (gfx950) -- Round 4.
// B=16384, N=12, D=128, H=4, hd=32. fp32 in/out, bf16 MFMA internally.
//
// R4 = R3 + fix: vT pad entries j=12,13 of each row are zeroed at kernel
// start. R3 left them uninitialized; LDS garbage can be NaN/inf bf16 and
// MFMA computes NaN*0 = NaN even though the matching P entries are 0.
//
// R3 structure (kept): 2 barriers, no LDS prologue (masks/biases straight
// to registers), phase-2 softmax fully in-register (ds_swizzle butterfly,
// in-register normalization, no rls round-trip), P overlays the wave's own
// dead ks rows, LDS 39.5KB -> 4 WG/CU (__launch_bounds__(256,4)).

typedef unsigned short u16;
typedef unsigned int   u32;
typedef short bf16x8 __attribute__((ext_vector_type(8)));   // 8 bf16 = 4 VGPRs
typedef float f32x4  __attribute__((ext_vector_type(4)));

#define MFMA(a, b, c) __builtin_amdgcn_mfma_f32_16x16x32_bf16((a), (b), (c), 0, 0, 0)

#define BPW   4            // batches per workgroup (1 per wave in phase 2)
#define ROWS  (BPW * 12)   // 48 joint-rows per WG
#define XPAD  136          // q/k/ctx row stride (bf16): 272B, 16B-aligned
#define VPAD  14           // vT row stride: 28B, word coeff 7 (gcd(7,32)=1 -> conflict-free)
#define PPAD  24           // P row stride: 48B, 16B-aligned -> b128 reads, 2-way banks (free)

struct SMem {
    u16 qs[ROWS * XPAD];        // q rows [48][128]; phase-2 ctx overlays per-head
    u16 ks[ROWS * XPAD];        // k rows; phase-2: per-wave P overlay (dead after QK)
    u16 vT[BPW * 128 * VPAD];   // per batch [feat][joint pad 14]
};                              // 13056 + 13056 + 14336 = 40448 B -> 4 WG/CU

#define SWZ(x, patt) __int_as_float(__builtin_amdgcn_ds_swizzle(__float_as_int(x), (patt)))

__device__ __forceinline__ u16 f2b(float f) {   // fp32 -> bf16 RNE
    unsigned u = __builtin_bit_cast(unsigned, f);
    return (u16)((u + 0x7fffu + ((u >> 16) & 1u)) >> 16);
}

__device__ __forceinline__ void st4(u16* p, float a, float b, float c, float d) {
    ushort4 v; v.x = f2b(a); v.y = f2b(b); v.z = f2b(c); v.w = f2b(d);
    *(ushort4*)p = v;   // ds_write_b64
}

__device__ __forceinline__ bf16x8 pack8(float4 a, float4 b) {
    bf16x8 r;
    r[0] = (short)f2b(a.x); r[1] = (short)f2b(a.y);
    r[2] = (short)f2b(a.z); r[3] = (short)f2b(a.w);
    r[4] = (short)f2b(b.x); r[5] = (short)f2b(b.y);
    r[6] = (short)f2b(b.z); r[7] = (short)f2b(b.w);
    return r;
}

__global__ void prep_w(const float* __restrict__ Wq, const float* __restrict__ Wk,
                       const float* __restrict__ Wv, const float* __restrict__ Wo,
                       u16* __restrict__ wbf) {
    int i = blockIdx.x * 256 + threadIdx.x;     // 0..16383
    wbf[i]         = f2b(Wq[i]);
    wbf[16384 + i] = f2b(Wk[i]);
    wbf[32768 + i] = f2b(Wv[i]);
    wbf[49152 + i] = f2b(Wo[i]);
}

__global__ __launch_bounds__(256, 4) void cja_main(
    const float* __restrict__ x, const float* __restrict__ vis,
    const float* __restrict__ bq, const float* __restrict__ bk,
    const float* __restrict__ bv, const float* __restrict__ bo,
    const float* __restrict__ bias_scale, const float* __restrict__ adj,
    const u16* __restrict__ wbf, float* __restrict__ out)
{
    __shared__ SMem sm;

    const int tid  = threadIdx.x;
    const int wave = tid >> 6;
    const int lane = tid & 63;
    const int lq   = lane >> 4;      // quadrant 0..3
    const int lm   = lane & 15;      // 0..15
    const int b0   = blockIdx.x * BPW;

    // -------- vT pad zeroing (j=12,13 per row): MFMA reads these; LDS
    // garbage can be NaN bf16 and NaN*0=NaN (the R3 bug). 2 stores/thread.
    #pragma unroll
    for (int z = 0; z < 2; z++) {
        int i = tid + z * 256;                         // row 0..511
        *(u32*)(sm.vT + i * VPAD + 12) = 0u;           // byte 28i+24: 4B-aligned
    }

    // -------- Early register loads (tiny, independent, L2-hot) --------------
    const float L2E = 1.4426950408889634f;
    const float scale = bias_scale[0] * L2E;
    float vv = 1.0f;
    if (lm < 12) vv = vis[(size_t)(b0 + wave) * 12 + lm];
    const float vism = 10.0f * L2E * (1.0f - vv);
    float bias_b[4];
    #pragma unroll
    for (int r = 0; r < 4; r++) {
        int n  = lq * 4 + r;
        int nc = (n < 12) ? n : 11;                    // clamp pad rows (discarded)
        bias_b[r] = (lm < 12) ? adj[nc * 12 + lm] * scale : -1e30f;  // key-pad mask
    }

    // ---------------- Phase 1: fused Q/K/V GEMMs (x from global) ------------
    {
        const u16* Wq_b = wbf;
        const u16* Wk_b = wbf + 16384;
        const u16* Wv_b = wbf + 32768;
        const float* xw = x + (size_t)b0 * 1536;
        f32x4 accq[2][3], acck[2][3], accv[3][2];
        #pragma unroll
        for (int i = 0; i < 2; i++)
            #pragma unroll
            for (int j = 0; j < 3; j++) { accq[i][j] = (f32x4){0,0,0,0}; acck[i][j] = (f32x4){0,0,0,0}; }
        #pragma unroll
        for (int i = 0; i < 3; i++)
            #pragma unroll
            for (int j = 0; j < 2; j++) accv[i][j] = (f32x4){0,0,0,0};

        const int mrow0 = wave * 32 + lm;
        const int mrow1 = mrow0 + 16;
        #pragma unroll
        for (int ks2 = 0; ks2 < 4; ks2++) {
            const int koff = ks2 * 32 + lq * 8;
            bf16x8 xf[3];
            #pragma unroll
            for (int nt = 0; nt < 3; nt++) {
                const float* xp = xw + (nt * 16 + lm) * 128 + koff;
                float4 u0 = *(const float4*)xp;
                float4 u1 = *(const float4*)(xp + 4);
                xf[nt] = pack8(u0, u1);
            }
            bf16x8 wq0 = *(const bf16x8*)(Wq_b + mrow0 * 128 + koff);
            bf16x8 wq1 = *(const bf16x8*)(Wq_b + mrow1 * 128 + koff);
            bf16x8 wk0 = *(const bf16x8*)(Wk_b + mrow0 * 128 + koff);
            bf16x8 wk1 = *(const bf16x8*)(Wk_b + mrow1 * 128 + koff);
            bf16x8 wv0 = *(const bf16x8*)(Wv_b + mrow0 * 128 + koff);
            bf16x8 wv1 = *(const bf16x8*)(Wv_b + mrow1 * 128 + koff);
            #pragma unroll
            for (int nt = 0; nt < 3; nt++) {
                accq[0][nt] = MFMA(wq0, xf[nt], accq[0][nt]);   // C[e,n] = Wq . x^T
                accq[1][nt] = MFMA(wq1, xf[nt], accq[1][nt]);
                acck[0][nt] = MFMA(wk0, xf[nt], acck[0][nt]);
                acck[1][nt] = MFMA(wk1, xf[nt], acck[1][nt]);
                accv[nt][0] = MFMA(xf[nt], wv0, accv[nt][0]);   // C[n,e] = x . Wv^T
                accv[nt][1] = MFMA(xf[nt], wv1, accv[nt][1]);
            }
        }
        // epilogue Q/K: transposed store -> row-major [joint-row][feat]
        #pragma unroll
        for (int mi = 0; mi < 2; mi++) {
            const int e0 = (wave * 2 + mi) * 16 + lq * 4;
            float4 bq4 = *(const float4*)(bq + e0);
            float4 bk4 = *(const float4*)(bk + e0);
            #pragma unroll
            for (int nt = 0; nt < 3; nt++) {
                const int n = nt * 16 + lm;
                st4(sm.qs + n * XPAD + e0, accq[mi][nt][0]+bq4.x, accq[mi][nt][1]+bq4.y,
                                           accq[mi][nt][2]+bq4.z, accq[mi][nt][3]+bq4.w);
                st4(sm.ks + n * XPAD + e0, acck[mi][nt][0]+bk4.x, acck[mi][nt][1]+bk4.y,
                                           acck[mi][nt][2]+bk4.z, acck[mi][nt][3]+bk4.w);
            }
        }
        // epilogue V: scatter -> vT[batch][feat][joint], stride 14 (gcd(7,32)=1)
        #pragma unroll
        for (int nt2 = 0; nt2 < 2; nt2++) {
            const int e = (wave * 2 + nt2) * 16 + lm;
            const float bvv = bv[e];
            #pragma unroll
            for (int mt = 0; mt < 3; mt++) {
                #pragma unroll
                for (int r = 0; r < 4; r++) {
                    int n = mt * 16 + lq * 4 + r;
                    int bb = n / 12, j = n - bb * 12;
                    sm.vT[bb * (128 * VPAD) + e * VPAD + j] = f2b(accv[mt][nt2][r] + bvv);
                }
            }
        }
    }
    __syncthreads();

    // ---------------- Phase 2: attention (wave w owns batch w) --------------
    {
        const int bl   = wave;
        const int nql  = (lm < 12) ? lm : 11;              // clamp: no OOB reads
        const u16* qrowp = sm.qs + (bl * 12 + nql) * XPAD;
        const u16* krowp = sm.ks + (bl * 12 + nql) * XPAD;
        u16* Pw = sm.ks + bl * 12 * XPAD;                  // overlay: ks dead after QK
        const u16* vTb = sm.vT + bl * (128 * VPAD);
        const float SC2 = 0.2550348606381560f;             // (1/sqrt(32))*log2(e)
        const bf16x8 z8 = {0,0,0,0,0,0,0,0};

        // all 4 score MFMAs up-front (independent)
        bf16x8 qa[4], kb[4];
        #pragma unroll
        for (int h = 0; h < 4; h++) {
            qa[h] = *(const bf16x8*)(qrowp + h * 32 + lq * 8);
            kb[h] = *(const bf16x8*)(krowp + h * 32 + lq * 8);
        }
        f32x4 sc[4];
        #pragma unroll
        for (int h = 0; h < 4; h++) sc[h] = MFMA(qa[h], kb[h], ((f32x4){0,0,0,0}));

        // 16 concurrent softmax chains; normalize in-register
        float p[4][4];
        #pragma unroll
        for (int h = 0; h < 4; h++)
            #pragma unroll
            for (int r = 0; r < 4; r++)
                p[h][r] = __builtin_amdgcn_exp2f(sc[h][r] * SC2 + bias_b[r] - vism);
        #pragma unroll
        for (int h = 0; h < 4; h++)
            #pragma unroll
            for (int r = 0; r < 4; r++) {
                float l = p[h][r];
                l += SWZ(l, 0x041F);                       // xor 1 within 16
                l += SWZ(l, 0x081F);                       // xor 2
                l += SWZ(l, 0x101F);                       // xor 4
                l += SWZ(l, 0x201F);                       // xor 8
                p[h][r] *= __builtin_amdgcn_rcpf(l);
            }
        #pragma unroll
        for (int h = 0; h < 4; h++)
            #pragma unroll
            for (int r = 0; r < 4; r++)
                Pw[h * (16 * PPAD) + (lq * 4 + r) * PPAD + lm] = f2b(p[h][r]);

        // PV: ctx^T = v^T . P^T, K-extent 16 (quads 2,3 zero-masked)
        #pragma unroll
        for (int h = 0; h < 4; h++) {
            bf16x8 pb = z8;
            if (lq < 2)
                pb = *(const bf16x8*)(Pw + h * (16 * PPAD) + lm * PPAD + lq * 8);
            #pragma unroll
            for (int mt = 0; mt < 2; mt++) {
                bf16x8 va = z8;
                if (lq < 2) {
                    const u16* vp = vTb + (h * 32 + mt * 16 + lm) * VPAD + lq * 8;
                    uint4 w;                               // rows 28B -> u32 loads
                    w.x = *(const u32*)(vp);
                    w.y = *(const u32*)(vp + 2);
                    w.z = *(const u32*)(vp + 4);
                    w.w = *(const u32*)(vp + 6);
                    va = __builtin_bit_cast(bf16x8, w);
                }
                f32x4 c = MFMA(va, pb, ((f32x4){0,0,0,0}));   // C[e',n]
                if (lm < 12) {                                 // ctx overlays qs
                    u16* d = sm.qs + (bl * 12 + lm) * XPAD + h * 32 + mt * 16 + lq * 4;
                    st4(d, c[0], c[1], c[2], c[3]);
                }
            }
        }
    }
    __syncthreads();

    // ---------------- Phase 3: output projection (transposed form) ----------
    {
        const u16* Wo_b = wbf + 49152;
        f32x4 acc[2][3];
        #pragma unroll
        for (int i = 0; i < 2; i++)
            #pragma unroll
            for (int j = 0; j < 3; j++) acc[i][j] = (f32x4){0,0,0,0};
        const int m0 = wave * 32 + lm;
        #pragma unroll
        for (int ks2 = 0; ks2 < 4; ks2++) {
            const int koff = ks2 * 32 + lq * 8;
            bf16x8 a0 = *(const bf16x8*)(Wo_b + m0 * 128 + koff);
            bf16x8 a1 = *(const bf16x8*)(Wo_b + (m0 + 16) * 128 + koff);
            #pragma unroll
            for (int nt = 0; nt < 3; nt++) {
                bf16x8 bfr = *(const bf16x8*)(sm.qs + (nt * 16 + lm) * XPAD + koff);
                acc[0][nt] = MFMA(a0, bfr, acc[0][nt]);
                acc[1][nt] = MFMA(a1, bfr, acc[1][nt]);
            }
        }
        #pragma unroll
        for (int mi = 0; mi < 2; mi++) {
            const int e0 = (wave * 2 + mi) * 16 + lq * 4;
            float4 bo4 = *(const float4*)(bo + e0);
            #pragma unroll
            for (int nt = 0; nt < 3; nt++) {
                const int n = nt * 16 + lm;
                float4 o;
                o.x = acc[mi][nt][0] + bo4.x;
                o.y = acc[mi][nt][1] + bo4.y;
                o.z = acc[mi][nt][2] + bo4.z;
                o.w = acc[mi][nt][3] + bo4.w;
                *(float4*)(out + ((size_t)(b0 * 12 + n) << 7) + e0) = o;
            }
        }
    }
}

extern "C" void kernel_launch(void* const* d_in, const int* in_sizes, int n_in,
                              void* d_out, int out_size, void* d_ws, size_t ws_size,
                              hipStream_t stream) {
    const float* x   = (const float*)d_in[0];
    const float* vis = (const float*)d_in[1];
    const float* Wq  = (const float*)d_in[2];
    const float* bq  = (const float*)d_in[3];
    const float* Wk  = (const float*)d_in[4];
    const float* bk  = (const float*)d_in[5];
    const float* Wv  = (const float*)d_in[6];
    const float* bv  = (const float*)d_in[7];
    const float* Wo  = (const float*)d_in[8];
    const float* bo  = (const float*)d_in[9];
    const float* bs  = (const float*)d_in[10];
    const float* adj = (const float*)d_in[11];
    u16* wbf = (u16*)d_ws;   // 4 x 128x128 bf16 = 128KB

    prep_w<<<64, 256, 0, stream>>>(Wq, Wk, Wv, Wo, wbf);
    cja_main<<<16384 / BPW, 256, 0, stream>>>(
        x, vis, bq, bk, bv, bo, bs, adj, wbf, (float*)d_out);
}